// Round 3
// baseline (346.696 us; speedup 1.0000x reference)
//
#include <hip/hip_runtime.h>

// LengthRegulator: predictor path in the reference is dead code
// (durations = target_durations overrides _pred). Outputs:
//   [0] padded [B, F, D] f32 = expand(x, target_durations)
//   [1] durations [B, T]     = target_durations as float
//
// Memory-bound: 256 MiB output write + ~117 MB x reads. Roofline ~55-70 us.

#define B_ 8
#define T_ 1024
#define D_ 1024
#define F_ 8192            // MAX_FRAMES = T * DMAX
#define ROWS_PER_BLOCK 32  // F_ % ROWS_PER_BLOCK == 0, chunks never cross batch

// native clang vector type: required by __builtin_nontemporal_store
// (HIP's float4 is a struct and is rejected by the builtin)
typedef float vfloat4 __attribute__((ext_vector_type(4)));

// Kernel A: per-batch inclusive scan of durations (LDS Hillis-Steele),
// scatter token index into tok_map[b, f] for f in [cum[t-1], cum[t]),
// -1 for invalid tail frames; also emit durations output chunk as float.
__global__ void __launch_bounds__(1024) dur_scan_kernel(
    const int* __restrict__ dur,     // [B, T]
    int* __restrict__ tok_map,       // [B, F] (workspace)
    float* __restrict__ out_dur)     // [B, T] (tail of d_out, float view)
{
    __shared__ int s[T_];
    const int b = blockIdx.x;
    const int t = threadIdx.x;

    const int d = dur[b * T_ + t];
    out_dur[b * T_ + t] = (float)d;

    s[t] = d;
    __syncthreads();
    #pragma unroll
    for (int off = 1; off < T_; off <<= 1) {
        int v = (t >= off) ? s[t - off] : 0;
        __syncthreads();
        s[t] += v;
        __syncthreads();
    }

    const int cum_t    = s[t];
    const int cum_prev = (t > 0) ? s[t - 1] : 0;
    const int total    = s[T_ - 1];

    int* tm = tok_map + b * F_;
    for (int f = cum_prev; f < cum_t; ++f) tm[f] = t;
    for (int f = total + t; f < F_; f += T_) tm[f] = -1;
}

// Kernel B: each block owns a contiguous chunk of 32 output rows (128 KiB).
// All 32 tok_map entries prefetched into LDS up front (kills the per-row
// dependent global load), then an unrolled stream-copy loop: one vfloat4 per
// thread per row, nontemporal stores (write-once 256 MiB stream), cached x
// loads (~3.5x reuse of each row now lands in L1 since same-token rows are
// block-local).
__global__ void __launch_bounds__(256) expand_kernel(
    const float* __restrict__ x,      // [B, T, D]
    const int* __restrict__ tok_map,  // [B, F]
    float* __restrict__ out)          // [B, F, D]
{
    __shared__ int s_tok[ROWS_PER_BLOCK];
    const int chunk = blockIdx.x * ROWS_PER_BLOCK;   // first row index (b*F_+f)
    const int b     = chunk >> 13;                   // F_ = 8192

    if (threadIdx.x < ROWS_PER_BLOCK)
        s_tok[threadIdx.x] = tok_map[chunk + threadIdx.x];
    __syncthreads();

    const vfloat4* xb  = reinterpret_cast<const vfloat4*>(x)
                       + (size_t)b * T_ * (D_ / 4) + threadIdx.x;
    vfloat4*       dst = reinterpret_cast<vfloat4*>(out)
                       + (size_t)chunk * (D_ / 4) + threadIdx.x;

    #pragma unroll 4
    for (int r = 0; r < ROWS_PER_BLOCK; ++r) {
        const int tok = s_tok[r];                    // wave-uniform
        vfloat4 v = (vfloat4)(0.f);
        if (tok >= 0) v = xb[(size_t)tok * (D_ / 4)];
        __builtin_nontemporal_store(v, dst + (size_t)r * (D_ / 4));
    }
}

extern "C" void kernel_launch(void* const* d_in, const int* in_sizes, int n_in,
                              void* d_out, int out_size, void* d_ws, size_t ws_size,
                              hipStream_t stream)
{
    const float* x   = (const float*)d_in[0];
    const int*   dur = (const int*)d_in[1];
    // d_in[2..11] (conv/LN/linear weights) are dead code in the reference.

    float* out     = (float*)d_out;
    float* out_dur = out + (size_t)B_ * F_ * D_;   // durations chunk
    int*   tok_map = (int*)d_ws;                   // B_*F_*4 = 256 KiB scratch

    dur_scan_kernel<<<B_, T_, 0, stream>>>(dur, tok_map, out_dur);
    expand_kernel<<<(B_ * F_) / ROWS_PER_BLOCK, 256, 0, stream>>>(x, tok_map, out);
}

// Round 4
// 342.825 us; speedup vs baseline: 1.0113x; 1.0113x over previous
//
#include <hip/hip_runtime.h>

// LengthRegulator: predictor path in the reference is dead code
// (durations = target_durations overrides _pred). Outputs:
//   [0] padded [B, F, D] f32 = expand(x, target_durations)
//   [1] durations [B, T]     = target_durations as float
//
// Memory-bound: 268 MB output write + ~35-117 MB x reads. Kernel roofline
// ~50-60 us; harness poison/restore adds ~220 us fixed to the timed window.
//
// R4: single change vs R3 — plain stores instead of nontemporal (the harness
// fill kernel proves plain stores reach 6.3 TB/s; NT was the only untested
// suspect in the R1->R3 -20us regression).

#define B_ 8
#define T_ 1024
#define D_ 1024
#define F_ 8192            // MAX_FRAMES = T * DMAX
#define ROWS_PER_BLOCK 32  // F_ % ROWS_PER_BLOCK == 0, chunks never cross batch

typedef float vfloat4 __attribute__((ext_vector_type(4)));

// Kernel A: per-batch inclusive scan of durations (LDS Hillis-Steele),
// scatter token index into tok_map[b, f] for f in [cum[t-1], cum[t]),
// -1 for invalid tail frames; also emit durations output chunk as float.
__global__ void __launch_bounds__(1024) dur_scan_kernel(
    const int* __restrict__ dur,     // [B, T]
    int* __restrict__ tok_map,       // [B, F] (workspace)
    float* __restrict__ out_dur)     // [B, T] (tail of d_out, float view)
{
    __shared__ int s[T_];
    const int b = blockIdx.x;
    const int t = threadIdx.x;

    const int d = dur[b * T_ + t];
    out_dur[b * T_ + t] = (float)d;

    s[t] = d;
    __syncthreads();
    #pragma unroll
    for (int off = 1; off < T_; off <<= 1) {
        int v = (t >= off) ? s[t - off] : 0;
        __syncthreads();
        s[t] += v;
        __syncthreads();
    }

    const int cum_t    = s[t];
    const int cum_prev = (t > 0) ? s[t - 1] : 0;
    const int total    = s[T_ - 1];

    int* tm = tok_map + b * F_;
    for (int f = cum_prev; f < cum_t; ++f) tm[f] = t;
    for (int f = total + t; f < F_; f += T_) tm[f] = -1;
}

// Kernel B: each block owns a contiguous chunk of 32 output rows (128 KiB).
// All 32 tok_map entries prefetched into LDS up front, then an unrolled
// stream-copy loop: one vfloat4 per thread per row, PLAIN stores (match the
// proven 6.3 TB/s fill path), cached x loads (same-token rows are block-local
// so the ~3.5x reuse of each x row lands in L1/L2).
__global__ void __launch_bounds__(256) expand_kernel(
    const float* __restrict__ x,      // [B, T, D]
    const int* __restrict__ tok_map,  // [B, F]
    float* __restrict__ out)          // [B, F, D]
{
    __shared__ int s_tok[ROWS_PER_BLOCK];
    const int chunk = blockIdx.x * ROWS_PER_BLOCK;   // first row index (b*F_+f)
    const int b     = chunk >> 13;                   // F_ = 8192

    if (threadIdx.x < ROWS_PER_BLOCK)
        s_tok[threadIdx.x] = tok_map[chunk + threadIdx.x];
    __syncthreads();

    const vfloat4* xb  = reinterpret_cast<const vfloat4*>(x)
                       + (size_t)b * T_ * (D_ / 4) + threadIdx.x;
    vfloat4*       dst = reinterpret_cast<vfloat4*>(out)
                       + (size_t)chunk * (D_ / 4) + threadIdx.x;

    #pragma unroll 4
    for (int r = 0; r < ROWS_PER_BLOCK; ++r) {
        const int tok = s_tok[r];                    // wave-uniform
        vfloat4 v = (vfloat4)(0.f);
        if (tok >= 0) v = xb[(size_t)tok * (D_ / 4)];
        dst[(size_t)r * (D_ / 4)] = v;               // plain global_store_dwordx4
    }
}

extern "C" void kernel_launch(void* const* d_in, const int* in_sizes, int n_in,
                              void* d_out, int out_size, void* d_ws, size_t ws_size,
                              hipStream_t stream)
{
    const float* x   = (const float*)d_in[0];
    const int*   dur = (const int*)d_in[1];
    // d_in[2..11] (conv/LN/linear weights) are dead code in the reference.

    float* out     = (float*)d_out;
    float* out_dur = out + (size_t)B_ * F_ * D_;   // durations chunk
    int*   tok_map = (int*)d_ws;                   // B_*F_*4 = 256 KiB scratch

    dur_scan_kernel<<<B_, T_, 0, stream>>>(dur, tok_map, out_dur);
    expand_kernel<<<(B_ * F_) / ROWS_PER_BLOCK, 256, 0, stream>>>(x, tok_map, out);
}

// Round 5
// 339.277 us; speedup vs baseline: 1.0219x; 1.0105x over previous
//
#include <hip/hip_runtime.h>

// LengthRegulator: predictor path in the reference is dead code
// (durations = target_durations overrides _pred). Outputs:
//   [0] padded [B, F, D] f32 = expand(x, target_durations)
//   [1] durations [B, T]     = target_durations as float
//
// Memory-bound: 268 MB output write + ~32 MB HBM x reads -> ~50 us kernel
// roofline. Harness poison fill (1.07 GB, ~170 us) + input restores are
// inside the timed window (~210 us floor).
//
// R5: single change vs R4 — branchless register-staged copy loop. The
// per-row wave-uniform branch (if tok>=0) forced LDS-wait + s_cbranch per
// row, breaking load clustering. Now: batch 8 toks into VGPRs, 8
// unconditional clamped loads (invalid rows read row 0 = L1 hit), 8
// v_cndmask zero-selects, 8 stores. Loads cluster into one vmcnt batch.

#define B_ 8
#define T_ 1024
#define D_ 1024
#define F_ 8192            // MAX_FRAMES = T * DMAX
#define ROWS_PER_BLOCK 32  // F_ % ROWS_PER_BLOCK == 0, chunks never cross batch
#define RBATCH 8           // rows per register-staged batch

typedef float vfloat4 __attribute__((ext_vector_type(4)));

// Kernel A: per-batch inclusive scan of durations (LDS Hillis-Steele),
// scatter token index into tok_map[b, f] for f in [cum[t-1], cum[t]),
// -1 for invalid tail frames; also emit durations output chunk as float.
__global__ void __launch_bounds__(1024) dur_scan_kernel(
    const int* __restrict__ dur,     // [B, T]
    int* __restrict__ tok_map,       // [B, F] (workspace)
    float* __restrict__ out_dur)     // [B, T] (tail of d_out, float view)
{
    __shared__ int s[T_];
    const int b = blockIdx.x;
    const int t = threadIdx.x;

    const int d = dur[b * T_ + t];
    out_dur[b * T_ + t] = (float)d;

    s[t] = d;
    __syncthreads();
    #pragma unroll
    for (int off = 1; off < T_; off <<= 1) {
        int v = (t >= off) ? s[t - off] : 0;
        __syncthreads();
        s[t] += v;
        __syncthreads();
    }

    const int cum_t    = s[t];
    const int cum_prev = (t > 0) ? s[t - 1] : 0;
    const int total    = s[T_ - 1];

    int* tm = tok_map + b * F_;
    for (int f = cum_prev; f < cum_t; ++f) tm[f] = t;
    for (int f = total + t; f < F_; f += T_) tm[f] = -1;
}

// Kernel B: each block owns 32 contiguous output rows (128 KiB). tok values
// staged LDS -> VGPR in batches of 8; loads unconditional (clamped) so the
// compiler can cluster them; zero-select via cndmask; no branches in body.
__global__ void __launch_bounds__(256) expand_kernel(
    const float* __restrict__ x,      // [B, T, D]
    const int* __restrict__ tok_map,  // [B, F]
    float* __restrict__ out)          // [B, F, D]
{
    __shared__ int s_tok[ROWS_PER_BLOCK];
    const int chunk = blockIdx.x * ROWS_PER_BLOCK;   // first row index (b*F_+f)
    const int b     = chunk >> 13;                   // F_ = 8192

    if (threadIdx.x < ROWS_PER_BLOCK)
        s_tok[threadIdx.x] = tok_map[chunk + threadIdx.x];
    __syncthreads();

    const vfloat4* xb  = reinterpret_cast<const vfloat4*>(x)
                       + (size_t)b * T_ * (D_ / 4) + threadIdx.x;
    vfloat4*       dst = reinterpret_cast<vfloat4*>(out)
                       + (size_t)chunk * (D_ / 4) + threadIdx.x;

    #pragma unroll
    for (int rr = 0; rr < ROWS_PER_BLOCK; rr += RBATCH) {
        int tk[RBATCH];
        vfloat4 v[RBATCH];
        #pragma unroll
        for (int i = 0; i < RBATCH; ++i) tk[i] = s_tok[rr + i];
        #pragma unroll
        for (int i = 0; i < RBATCH; ++i) {
            const int c = tk[i] < 0 ? 0 : tk[i];            // clamp: row 0, L1 hit
            v[i] = xb[(size_t)c * (D_ / 4)];                // unconditional load
        }
        #pragma unroll
        for (int i = 0; i < RBATCH; ++i) {
            v[i] = tk[i] < 0 ? (vfloat4)(0.f) : v[i];       // cndmask, no branch
            dst[(size_t)(rr + i) * (D_ / 4)] = v[i];
        }
    }
}

extern "C" void kernel_launch(void* const* d_in, const int* in_sizes, int n_in,
                              void* d_out, int out_size, void* d_ws, size_t ws_size,
                              hipStream_t stream)
{
    const float* x   = (const float*)d_in[0];
    const int*   dur = (const int*)d_in[1];
    // d_in[2..11] (conv/LN/linear weights) are dead code in the reference.

    float* out     = (float*)d_out;
    float* out_dur = out + (size_t)B_ * F_ * D_;   // durations chunk
    int*   tok_map = (int*)d_ws;                   // B_*F_*4 = 256 KiB scratch

    dur_scan_kernel<<<B_, T_, 0, stream>>>(dur, tok_map, out_dur);
    expand_kernel<<<(B_ * F_) / ROWS_PER_BLOCK, 256, 0, stream>>>(x, tok_map, out);
}

// Round 6
// 325.299 us; speedup vs baseline: 1.0658x; 1.0430x over previous
//
#include <hip/hip_runtime.h>

// LengthRegulator: predictor path in the reference is dead code
// (durations = target_durations overrides _pred). Outputs:
//   [0] padded [B, F, D] f32 = expand(x, target_durations)
//   [1] durations [B, T]     = target_durations as float
//
// R6: scatter formulation. Gather-expand (R1-R5) pays a dependent x-row
// load (HBM miss after the 1GB poison evicts LLC) before 44% of stores and
// plateaued ~2.5 TB/s. Now each token's block loads its row ONCE (x read
// exactly once, coalesced) and stores it dur times (independent pure write
// stream); invalid tail is a specialized pure zero-fill. No load->store
// dependence chains except one per token.

#define B_ 8
#define T_ 1024
#define D_ 1024
#define F_ 8192          // MAX_FRAMES = T * DMAX
#define DV4 (D_ / 4)     // 256 float4 per row
#define ZROWS 32         // rows per zero-fill block

typedef float vfloat4 __attribute__((ext_vector_type(4)));

// Kernel A: per-batch inclusive scan of durations (LDS Hillis-Steele).
// Emits cum[b,t] to workspace and the durations output chunk as float.
__global__ void __launch_bounds__(1024) dur_scan_kernel(
    const int* __restrict__ dur,     // [B, T]
    int* __restrict__ cum,           // [B, T] inclusive scan (workspace)
    float* __restrict__ out_dur)     // [B, T] (tail of d_out, float view)
{
    __shared__ int s[T_];
    const int b = blockIdx.x;
    const int t = threadIdx.x;

    const int d = dur[b * T_ + t];
    out_dur[b * T_ + t] = (float)d;

    s[t] = d;
    __syncthreads();
    #pragma unroll
    for (int off = 1; off < T_; off <<= 1) {
        int v = (t >= off) ? s[t - off] : 0;
        __syncthreads();
        s[t] += v;
        __syncthreads();
    }
    cum[b * T_ + t] = s[t];
}

// Kernel B: one block per token. Load the token's row once (coalesced,
// one vfloat4/thread), store it to output rows [cum[t-1], cum[t]).
// dur=0 blocks exit before touching x.
__global__ void __launch_bounds__(256) scatter_kernel(
    const float* __restrict__ x,     // [B, T, D]
    const int* __restrict__ cum,     // [B, T]
    float* __restrict__ out)         // [B, F, D]
{
    const int bt = blockIdx.x;           // b * T_ + t
    const int b  = bt >> 10;
    const int t  = bt & (T_ - 1);

    const int c1 = cum[bt];              // wave-uniform scalar loads
    const int c0 = t ? cum[bt - 1] : 0;
    if (c0 == c1) return;

    const vfloat4 v = reinterpret_cast<const vfloat4*>(x)[(size_t)bt * DV4 + threadIdx.x];
    vfloat4* dstb = reinterpret_cast<vfloat4*>(out)
                  + (size_t)b * F_ * DV4 + threadIdx.x;
    for (int r = c0; r < c1; ++r)        // <= 7 independent row stores
        dstb[(size_t)r * DV4] = v;
}

// Kernel C: zero the invalid tail frames [total, F) per batch. Pure store
// stream (the proven 6.3 TB/s pattern). Fully-valid chunks exit instantly.
__global__ void __launch_bounds__(256) zerofill_kernel(
    const int* __restrict__ cum,     // [B, T]
    float* __restrict__ out)         // [B, F, D]
{
    const int chunk = blockIdx.x * ZROWS;    // global row index b*F_+f
    const int b     = chunk >> 13;           // F_ = 8192
    const int f0    = chunk & (F_ - 1);
    const int total = cum[b * T_ + T_ - 1];  // scalar load
    if (f0 + ZROWS <= total) return;

    vfloat4* dstb = reinterpret_cast<vfloat4*>(out)
                  + (size_t)chunk * DV4 + threadIdx.x;
    #pragma unroll 4
    for (int r = 0; r < ZROWS; ++r) {
        if (f0 + r >= total)
            dstb[(size_t)r * DV4] = (vfloat4)(0.f);
    }
}

extern "C" void kernel_launch(void* const* d_in, const int* in_sizes, int n_in,
                              void* d_out, int out_size, void* d_ws, size_t ws_size,
                              hipStream_t stream)
{
    const float* x   = (const float*)d_in[0];
    const int*   dur = (const int*)d_in[1];
    // d_in[2..11] (conv/LN/linear weights) are dead code in the reference.

    float* out     = (float*)d_out;
    float* out_dur = out + (size_t)B_ * F_ * D_;   // durations chunk
    int*   cum     = (int*)d_ws;                   // B_*T_*4 = 32 KiB scratch

    dur_scan_kernel<<<B_, T_, 0, stream>>>(dur, cum, out_dur);
    scatter_kernel<<<B_ * T_, 256, 0, stream>>>(x, cum, out);
    zerofill_kernel<<<(B_ * F_) / ZROWS, 256, 0, stream>>>(cum, out);
}

// Round 7
// 323.412 us; speedup vs baseline: 1.0720x; 1.0058x over previous
//
#include <hip/hip_runtime.h>

// LengthRegulator: predictor path in the reference is dead code
// (durations = target_durations overrides _pred). Outputs:
//   [0] padded [B, F, D] f32 = expand(x, target_durations)
//   [1] durations [B, T]     = target_durations as float
//
// R7: fuse scatter + zerofill into ONE dispatch. R6's serialized launches
// drain the write pipe between kernels; fused, the pure-store zero blocks
// co-schedule with load-gated scatter blocks and fill the bandwidth gaps.
// Total traffic: ~28 MB read + 268 MB write ≈ 47 us @ 6.3 TB/s.

#define B_ 8
#define T_ 1024
#define D_ 1024
#define F_ 8192          // MAX_FRAMES = T * DMAX
#define DV4 (D_ / 4)     // 256 float4 per row
#define ZROWS 32         // rows per zero-fill block
#define NSCAT (B_ * T_)            // 8192 scatter blocks
#define NZERO ((B_ * F_) / ZROWS)  // 2048 zero blocks

typedef float vfloat4 __attribute__((ext_vector_type(4)));

// Kernel A: per-batch inclusive scan of durations (LDS Hillis-Steele).
// Emits cum[b,t] to workspace and the durations output chunk as float.
__global__ void __launch_bounds__(1024) dur_scan_kernel(
    const int* __restrict__ dur,     // [B, T]
    int* __restrict__ cum,           // [B, T] inclusive scan (workspace)
    float* __restrict__ out_dur)     // [B, T] (tail of d_out, float view)
{
    __shared__ int s[T_];
    const int b = blockIdx.x;
    const int t = threadIdx.x;

    const int d = dur[b * T_ + t];
    out_dur[b * T_ + t] = (float)d;

    s[t] = d;
    __syncthreads();
    #pragma unroll
    for (int off = 1; off < T_; off <<= 1) {
        int v = (t >= off) ? s[t - off] : 0;
        __syncthreads();
        s[t] += v;
        __syncthreads();
    }
    cum[b * T_ + t] = s[t];
}

// Kernel B (fused): blocks [0, NSCAT) scatter token rows; blocks
// [NSCAT, NSCAT+NZERO) zero the invalid tail. Block-level branch only.
__global__ void __launch_bounds__(256) expand_fused_kernel(
    const float* __restrict__ x,     // [B, T, D]
    const int* __restrict__ cum,     // [B, T]
    float* __restrict__ out)         // [B, F, D]
{
    const int idx = blockIdx.x;
    if (idx < NSCAT) {
        // --- scatter: one block per token, row loaded once, stored dur times
        const int bt = idx;              // b * T_ + t
        const int b  = bt >> 10;
        const int t  = bt & (T_ - 1);

        const int c1 = cum[bt];          // wave-uniform scalar loads
        const int c0 = t ? cum[bt - 1] : 0;
        if (c0 == c1) return;

        const vfloat4 v =
            reinterpret_cast<const vfloat4*>(x)[(size_t)bt * DV4 + threadIdx.x];
        vfloat4* dstb = reinterpret_cast<vfloat4*>(out)
                      + (size_t)b * F_ * DV4 + threadIdx.x;
        for (int r = c0; r < c1; ++r)    // <= 7 independent row stores
            dstb[(size_t)r * DV4] = v;
    } else {
        // --- zerofill: pure store stream over invalid tail rows
        const int chunk = (idx - NSCAT) * ZROWS;  // global row index b*F_+f
        const int b     = chunk >> 13;            // F_ = 8192
        const int f0    = chunk & (F_ - 1);
        const int total = cum[b * T_ + T_ - 1];   // scalar load
        if (f0 + ZROWS <= total) return;

        vfloat4* dstb = reinterpret_cast<vfloat4*>(out)
                      + (size_t)chunk * DV4 + threadIdx.x;
        #pragma unroll 4
        for (int r = 0; r < ZROWS; ++r) {
            if (f0 + r >= total)
                dstb[(size_t)r * DV4] = (vfloat4)(0.f);
        }
    }
}

extern "C" void kernel_launch(void* const* d_in, const int* in_sizes, int n_in,
                              void* d_out, int out_size, void* d_ws, size_t ws_size,
                              hipStream_t stream)
{
    const float* x   = (const float*)d_in[0];
    const int*   dur = (const int*)d_in[1];
    // d_in[2..11] (conv/LN/linear weights) are dead code in the reference.

    float* out     = (float*)d_out;
    float* out_dur = out + (size_t)B_ * F_ * D_;   // durations chunk
    int*   cum     = (int*)d_ws;                   // B_*T_*4 = 32 KiB scratch

    dur_scan_kernel<<<B_, T_, 0, stream>>>(dur, cum, out_dur);
    expand_fused_kernel<<<NSCAT + NZERO, 256, 0, stream>>>(x, cum, out);
}